// Round 4
// baseline (283.052 us; speedup 1.0000x reference)
//
#include <hip/hip_runtime.h>
#include <hip/hip_bf16.h>

#define T_SEQ   2048
#define D_MODEL 1024
#define N_HEADS 16
#define HEAD_DIM 64
#define BT      8192   // B*T
#define N3D     3072

using short8  = __attribute__((ext_vector_type(8))) short;
using short4v = __attribute__((ext_vector_type(4))) short;
using floatx4 = __attribute__((ext_vector_type(4))) float;

#define QSCALE 0.18033688f  // 0.125 * log2(e): folded into Q at QKV epilogue

__device__ __forceinline__ unsigned short rne_bf16(float f) {
  unsigned int u = __float_as_uint(f);
  u = (u + 0x7fffu + ((u >> 16) & 1u)) >> 16;
  return (unsigned short)u;
}

// async global->LDS, 16B per lane; dest = wave-uniform base + lane*16 (m104)
__device__ __forceinline__ void gload_lds16(const unsigned short* g,
                                            unsigned short* l) {
  __builtin_amdgcn_global_load_lds(
      (const __attribute__((address_space(1))) void*)g,
      (__attribute__((address_space(3))) void*)l, 16, 0, 0);
}

// ---------------- elementwise fp32 -> bf16 ----------------
__global__ __launch_bounds__(256) void k_convert(const float* __restrict__ in,
                                                 unsigned short* __restrict__ out) {
  size_t i = ((size_t)blockIdx.x * 256 + threadIdx.x) * 8;
  float4 a = *(const float4*)(in + i);
  float4 b = *(const float4*)(in + i + 4);
  short8 v;
  v[0] = (short)rne_bf16(a.x); v[1] = (short)rne_bf16(a.y);
  v[2] = (short)rne_bf16(a.z); v[3] = (short)rne_bf16(a.w);
  v[4] = (short)rne_bf16(b.x); v[5] = (short)rne_bf16(b.y);
  v[6] = (short)rne_bf16(b.z); v[7] = (short)rne_bf16(b.w);
  *(short8*)(((short*)out) + i) = v;
}

// ------------- tiled transpose + convert -------------
__global__ __launch_bounds__(256) void k_transpose_convert(
    const float* __restrict__ in, unsigned short* __restrict__ out_hi,
    int R, int C) {
  __shared__ float tile[64][65];
  int tiles_c = C >> 6;
  int r0 = (blockIdx.x / tiles_c) << 6;
  int c0 = (blockIdx.x % tiles_c) << 6;
  int tid = threadIdx.x;
#pragma unroll
  for (int i = 0; i < 16; ++i) {
    int idx = tid + i * 256;
    int r = idx >> 6, c = idx & 63;
    tile[r][c] = in[(size_t)(r0 + r) * C + c0 + c];
  }
  __syncthreads();
#pragma unroll
  for (int i = 0; i < 16; ++i) {
    int idx = tid + i * 256;
    int orow = idx >> 6, oc = idx & 63;
    out_hi[(size_t)(c0 + orow) * R + r0 + oc] = rne_bf16(tile[oc][orow]);
  }
}

// ---------------- QKV GEMM (bf16 MFMA, BK=64, XCD-swizzled grid) ----------
// R11: BK 32->64 halves the barrier count (the vmcnt(0)+lgkmcnt(0) drain
// before each s_barrier is the m97-structure's ~20% stall; same loads,
// same MFMAs, half the drains). LDS swizzle re-derived for 128B rows:
// physical k-group = logical ^ (row&7); every consecutive-8-lane subgroup
// spans all 8 bank-quads -> conflict-free (expect SQ_LDS_BANK_CONFLICT=0).
// T1: bijective XCD swizzle (1536%8==0) so the 24 n-blocks sharing an
// A-panel run on one XCD's L2.
__global__ __launch_bounds__(256) void k_qkv_gemm(
    const unsigned short* __restrict__ A, const unsigned short* __restrict__ Bt,
    const float* __restrict__ bias,
    unsigned short* __restrict__ Qo, unsigned short* __restrict__ Ko,
    unsigned short* __restrict__ Vt) {
  __shared__ __align__(16) unsigned short As[128 * 64];
  __shared__ __align__(16) unsigned short Bs[128 * 64];
  int tid = threadIdx.x;
  int wg = (blockIdx.x & 7) * 192 + (blockIdx.x >> 3);  // XCD-chunked, bijective
  int m0 = (wg / 24) * 128;
  int n0 = (wg % 24) * 128;
  int w = tid >> 6, lane = tid & 63, quad = lane >> 4, l16 = lane & 15;
  int wm = (w >> 1) * 64, wn = (w & 1) * 64;
  floatx4 acc[4][4] = {};

  // staging: slot s = tid + i*256 (i<4); row = s>>3, phys group = s&7,
  // logical group = (s&7) ^ (row&7)  (i-invariant since i*256 ≡ 0 mod 8 rows)
  int r0 = tid >> 3;
  int gsh = (((tid & 7) ^ (r0 & 7)) << 3);   // shorts offset of logical group

  // read offsets: logical group = ks*4+quad at row ra -> phys ^ (ra&7)
  int a_off[4][2], b_off[4][2];
#pragma unroll
  for (int t = 0; t < 4; ++t) {
    int ra = wm + t * 16 + l16, rb = wn + t * 16 + l16;
#pragma unroll
    for (int ks = 0; ks < 2; ++ks) {
      a_off[t][ks] = ra * 64 + (((ks * 4 + quad) ^ (ra & 7)) << 3);
      b_off[t][ks] = rb * 64 + (((ks * 4 + quad) ^ (rb & 7)) << 3);
    }
  }

  for (int k0 = 0; k0 < 1024; k0 += 64) {
#pragma unroll
    for (int i = 0; i < 4; ++i) {
      int sub = (tid & ~63) + i * 256;
      gload_lds16(A + (size_t)(m0 + r0 + i * 32) * 1024 + k0 + gsh,
                  &As[sub * 8]);
      gload_lds16(Bt + (size_t)(n0 + r0 + i * 32) * 1024 + k0 + gsh,
                  &Bs[sub * 8]);
    }
    __syncthreads();
#pragma unroll
    for (int ks = 0; ks < 2; ++ks) {
      short8 af[4], bfr[4];
#pragma unroll
      for (int mt = 0; mt < 4; ++mt) af[mt] = *(const short8*)(&As[a_off[mt][ks]]);
#pragma unroll
      for (int nt = 0; nt < 4; ++nt) bfr[nt] = *(const short8*)(&Bs[b_off[nt][ks]]);
#pragma unroll
      for (int mt = 0; mt < 4; ++mt)
#pragma unroll
        for (int nt = 0; nt < 4; ++nt)
          acc[mt][nt] = __builtin_amdgcn_mfma_f32_16x16x32_bf16(af[mt], bfr[nt],
                                                                acc[mt][nt], 0, 0, 0);
    }
    __syncthreads();
  }

#pragma unroll
  for (int nt = 0; nt < 4; ++nt) {
    int n = n0 + wn + nt * 16 + l16;
    float bv = bias[n];
    int which = n >> 10;           // 0=Q 1=K 2=V
    int nn = n & 1023;
    int h = nn >> 6, hd = nn & 63;
#pragma unroll
    for (int mt = 0; mt < 4; ++mt) {
      int mbase = m0 + wm + mt * 16 + quad * 4;
      int b = mbase >> 11;
      int t0 = mbase & 2047;
      int head = b * N_HEADS + h;
      if (which == 2) {
        short4v vv;
#pragma unroll
        for (int r = 0; r < 4; ++r) vv[r] = (short)rne_bf16(acc[mt][nt][r] + bv);
        *(short4v*)(&Vt[((size_t)head * HEAD_DIM + hd) * T_SEQ + t0]) = vv;
      } else {
        unsigned short* dst = (which == 0) ? Qo : Ko;
        float scl = (which == 0) ? QSCALE : 1.0f;
#pragma unroll
        for (int r = 0; r < 4; ++r)
          dst[((size_t)head * T_SEQ + t0 + r) * HEAD_DIM + hd] =
              rne_bf16((acc[mt][nt][r] + bv) * scl);
      }
    }
  }
}

// ---------------- flash attention (S^T form, T15 pipeline, QBLK=256) -------
// R10 (kept verbatim): 8 waves / 512 threads, 256 q-rows/block, grid 512,
// XCD-grouped heads. 93.5 us steady, FETCH 27MB, MfmaUtil 34.6.
__global__ __launch_bounds__(512, 4) void k_attn(
    const unsigned short* __restrict__ Q, const unsigned short* __restrict__ K,
    const unsigned short* __restrict__ Vt, unsigned short* __restrict__ Oo) {
  __shared__ __align__(16) unsigned short Klds[2][64 * 64];
  __shared__ __align__(16) unsigned short Vlds[3][64 * 64];
  int tid = threadIdx.x;
  int head = ((blockIdx.x & 7) << 3) + (blockIdx.x >> 6);  // XCD-grouped
  int qb = ((blockIdx.x >> 3) & 7) << 8;                   // 256 rows/block
  int b = head >> 4, h = head & 15;
  int w = tid >> 6, lane = tid & 63, quad = lane >> 4, l16 = lane & 15;
  const unsigned short* Qh = Q + (size_t)head * T_SEQ * HEAD_DIM;
  const unsigned short* Kh = K + (size_t)head * T_SEQ * HEAD_DIM;
  const unsigned short* Vh = Vt + (size_t)head * HEAD_DIM * T_SEQ;

  // Q B-frag: lane n=q=l16 holds d-elems quad*8+j (+32 per ks-half)
  short8 qf[2][2];
#pragma unroll
  for (int qi = 0; qi < 2; ++qi) {
    int qrow = qb + w * 32 + qi * 16 + l16;
#pragma unroll
    for (int ks = 0; ks < 2; ++ks)
      qf[qi][ks] = *(const short8*)(Qh + (size_t)qrow * 64 + ks * 32 + quad * 8);
  }

  short8 ones;
#pragma unroll
  for (int j = 0; j < 8; ++j) ones[j] = (short)0x3F80;  // bf16 1.0

  floatx4 O[2][4] = {};
  floatx4 Osum[2] = {};
  const floatx4 zf = {};

  // staging: slot = tid (512 slots x 16B = 8KB tile). Logical index
  // xs = lane ^ sg; K source row applies the tile permutation to xs.
  int sg = tid >> 6;                       // wave-uniform, 0..7
  int xs = lane ^ sg;
  int ntp = xs >> 4, mp = xs & 15;
  int ksrc = ((ntp >> 1) << 5) + ((mp >> 2) << 3) + ((ntp & 1) << 2) + (mp & 3);
  int vsrc = xs;                           // V^T row d
  int sub = tid & ~63;                     // wave-uniform slot base

  // loop-invariant swizzled LDS read offsets (short units): pu[ks][t]
  int pu[2][4];
#pragma unroll
  for (int ks = 0; ks < 2; ++ks) {
    int gk = ks * 4 + quad;
#pragma unroll
    for (int t = 0; t < 4; ++t)
      pu[ks][t] = (((gk << 6) + t * 16 + l16) ^ gk) << 3;
  }

  auto stageK = [&](unsigned short* dst, int kb) {
    gload_lds16(Kh + ((size_t)(kb * 64 + ksrc)) * 64 + sg * 8, dst + sub * 8);
  };
  auto stageV = [&](unsigned short* dst, int kb) {
    gload_lds16(Vh + (size_t)vsrc * T_SEQ + kb * 64 + sg * 8, dst + sub * 8);
  };

  short8 pPrev[2][2];   // P fragments of tile t-1 (carried across iterations)

  auto qk = [&](const unsigned short* Kb_, floatx4 (&s)[2][4]) {
#pragma unroll
    for (int ks = 0; ks < 2; ++ks) {
#pragma unroll
      for (int nt = 0; nt < 4; ++nt) {
        short8 kf = *(const short8*)(Kb_ + pu[ks][nt]);
        if (ks == 0) {
          s[0][nt] = __builtin_amdgcn_mfma_f32_16x16x32_bf16(kf, qf[0][0], zf, 0, 0, 0);
          s[1][nt] = __builtin_amdgcn_mfma_f32_16x16x32_bf16(kf, qf[1][0], zf, 0, 0, 0);
        } else {
          s[0][nt] = __builtin_amdgcn_mfma_f32_16x16x32_bf16(kf, qf[0][1], s[0][nt], 0, 0, 0);
          s[1][nt] = __builtin_amdgcn_mfma_f32_16x16x32_bf16(kf, qf[1][1], s[1][nt], 0, 0, 0);
        }
      }
    }
  };

  auto pv = [&](const unsigned short* Vb_) {
#pragma unroll
    for (int ks = 0; ks < 2; ++ks) {
      Osum[0] = __builtin_amdgcn_mfma_f32_16x16x32_bf16(ones, pPrev[0][ks], Osum[0], 0, 0, 0);
      Osum[1] = __builtin_amdgcn_mfma_f32_16x16x32_bf16(ones, pPrev[1][ks], Osum[1], 0, 0, 0);
#pragma unroll
      for (int dt = 0; dt < 4; ++dt) {
        short8 vf = *(const short8*)(Vb_ + pu[ks][dt]);
        O[0][dt] = __builtin_amdgcn_mfma_f32_16x16x32_bf16(vf, pPrev[0][ks], O[0][dt], 0, 0, 0);
        O[1][dt] = __builtin_amdgcn_mfma_f32_16x16x32_bf16(vf, pPrev[1][ks], O[1][dt], 0, 0, 0);
      }
    }
  };

  auto expPack = [&](floatx4 (&s)[2][4]) {
#pragma unroll
    for (int qi = 0; qi < 2; ++qi) {
      unsigned int dw[4][2];
#pragma unroll
      for (int nt = 0; nt < 4; ++nt) {
        float p0 = __builtin_amdgcn_exp2f(s[qi][nt][0]);
        float p1 = __builtin_amdgcn_exp2f(s[qi][nt][1]);
        float p2 = __builtin_amdgcn_exp2f(s[qi][nt][2]);
        float p3 = __builtin_amdgcn_exp2f(s[qi][nt][3]);
        __hip_bfloat162 lo2 = __float22bfloat162_rn(make_float2(p0, p1));
        __hip_bfloat162 hi2 = __float22bfloat162_rn(make_float2(p2, p3));
        dw[nt][0] = *(unsigned int*)&lo2;
        dw[nt][1] = *(unsigned int*)&hi2;
      }
#pragma unroll
      for (int ks = 0; ks < 2; ++ks) {
        union { unsigned int u[4]; short8 s8; } cv;
        cv.u[0] = dw[2 * ks][0];
        cv.u[1] = dw[2 * ks][1];
        cv.u[2] = dw[2 * ks + 1][0];
        cv.u[3] = dw[2 * ks + 1][1];
        pPrev[qi][ks] = cv.s8;
      }
    }
  };

  unsigned short* Kcur = &Klds[1][0];
  unsigned short* Koth = &Klds[0][0];
  unsigned short* Vp = &Vlds[0][0];
  unsigned short* Vc = &Vlds[1][0];
  unsigned short* Vn = &Vlds[2][0];

  // prologue: tile 0 (QK + pack only, no PV yet)
  stageK(Koth, 0); stageV(Vp, 0);
  __syncthreads();
  stageK(Kcur, 1); stageV(Vc, 1);
  {
    floatx4 s[2][4];
    qk(Koth, s);
    expPack(s);
  }
  __syncthreads();

#pragma unroll 1
  for (int t = 1; t < 32; ++t) {
    if (t < 31) { stageK(Koth, t + 1); stageV(Vn, t + 1); }
    floatx4 s[2][4];
    __builtin_amdgcn_s_setprio(1);
    qk(Kcur, s);        // QK(t)   — matrix pipe
    pv(Vp);             // PV(t-1) — matrix pipe, independent of s
    __builtin_amdgcn_s_setprio(0);
    expPack(s);         // exp2/pack(t) — VALU, overlaps PV drain
    __syncthreads();
    unsigned short* tk = Kcur; Kcur = Koth; Koth = tk;
    unsigned short* tv = Vp; Vp = Vc; Vc = Vn; Vn = tv;
  }
  pv(Vp);               // PV(31)

  // O^T layout: lane col q=l16, rows d = dt*16 + quad*4 + r -> b64 stores
#pragma unroll
  for (int qi = 0; qi < 2; ++qi) {
    float inv = 1.0f / Osum[qi][0];
    int t = qb + w * 32 + qi * 16 + l16;
    size_t rowo = ((size_t)(b * T_SEQ + t)) * D_MODEL + h * HEAD_DIM;
#pragma unroll
    for (int dt = 0; dt < 4; ++dt) {
      short4v ov;
#pragma unroll
      for (int r = 0; r < 4; ++r) ov[r] = (short)rne_bf16(O[qi][dt][r] * inv);
      *(short4v*)(&Oo[rowo + dt * 16 + quad * 4]) = ov;
    }
  }
}

// ---------------- proj GEMM (bf16 MFMA, BK=64, XCD-swizzled grid) ---------
__global__ __launch_bounds__(256) void k_proj_gemm(
    const unsigned short* __restrict__ A, const unsigned short* __restrict__ Bt,
    const float* __restrict__ bias, float* __restrict__ out) {
  __shared__ __align__(16) unsigned short As[128 * 64];
  __shared__ __align__(16) unsigned short Bs[128 * 64];
  int tid = threadIdx.x;
  int wg = (blockIdx.x & 7) * 64 + (blockIdx.x >> 3);   // XCD-chunked, bijective
  int m0 = (wg >> 3) * 128;
  int n0 = (wg & 7) * 128;
  int w = tid >> 6, lane = tid & 63, quad = lane >> 4, l16 = lane & 15;
  int wm = (w >> 1) * 64, wn = (w & 1) * 64;
  floatx4 acc[4][4] = {};

  int r0 = tid >> 3;
  int gsh = (((tid & 7) ^ (r0 & 7)) << 3);

  int a_off[4][2], b_off[4][2];
#pragma unroll
  for (int t = 0; t < 4; ++t) {
    int ra = wm + t * 16 + l16, rb = wn + t * 16 + l16;
#pragma unroll
    for (int ks = 0; ks < 2; ++ks) {
      a_off[t][ks] = ra * 64 + (((ks * 4 + quad) ^ (ra & 7)) << 3);
      b_off[t][ks] = rb * 64 + (((ks * 4 + quad) ^ (rb & 7)) << 3);
    }
  }

  for (int k0 = 0; k0 < 1024; k0 += 64) {
#pragma unroll
    for (int i = 0; i < 4; ++i) {
      int sub = (tid & ~63) + i * 256;
      gload_lds16(A + (size_t)(m0 + r0 + i * 32) * 1024 + k0 + gsh,
                  &As[sub * 8]);
      gload_lds16(Bt + (size_t)(n0 + r0 + i * 32) * 1024 + k0 + gsh,
                  &Bs[sub * 8]);
    }
    __syncthreads();
#pragma unroll
    for (int ks = 0; ks < 2; ++ks) {
      short8 af[4], bfr[4];
#pragma unroll
      for (int mt = 0; mt < 4; ++mt) af[mt] = *(const short8*)(&As[a_off[mt][ks]]);
#pragma unroll
      for (int nt = 0; nt < 4; ++nt) bfr[nt] = *(const short8*)(&Bs[b_off[nt][ks]]);
#pragma unroll
      for (int mt = 0; mt < 4; ++mt)
#pragma unroll
        for (int nt = 0; nt < 4; ++nt)
          acc[mt][nt] = __builtin_amdgcn_mfma_f32_16x16x32_bf16(af[mt], bfr[nt],
                                                                acc[mt][nt], 0, 0, 0);
    }
    __syncthreads();
  }

#pragma unroll
  for (int nt = 0; nt < 4; ++nt) {
    int n = n0 + wn + nt * 16 + l16;
    float bv = bias[n];
#pragma unroll
    for (int mt = 0; mt < 4; ++mt)
#pragma unroll
      for (int r = 0; r < 4; ++r) {
        int m = m0 + wm + mt * 16 + quad * 4 + r;
        out[(size_t)m * 1024 + n] = acc[mt][nt][r] + bv;
      }
  }
}

extern "C" void kernel_launch(void* const* d_in, const int* in_sizes, int n_in,
                              void* d_out, int out_size, void* d_ws, size_t ws_size,
                              hipStream_t stream) {
  const float* x     = (const float*)d_in[0];
  const float* wqkv  = (const float*)d_in[1];
  const float* bqkv  = (const float*)d_in[2];
  const float* wproj = (const float*)d_in[3];
  const float* bproj = (const float*)d_in[4];

  char* ws = (char*)d_ws;
  size_t off = 0;
  unsigned short* x_bf  = (unsigned short*)(ws + off); off += (size_t)BT * D_MODEL * 2;
  unsigned short* wq_T  = (unsigned short*)(ws + off); off += (size_t)N3D * D_MODEL * 2;
  unsigned short* wp_T  = (unsigned short*)(ws + off); off += (size_t)D_MODEL * D_MODEL * 2;
  unsigned short* Qb    = (unsigned short*)(ws + off); off += (size_t)BT * D_MODEL * 2;
  unsigned short* Kb    = (unsigned short*)(ws + off); off += (size_t)BT * D_MODEL * 2;
  unsigned short* Vt    = (unsigned short*)(ws + off); off += (size_t)BT * D_MODEL * 2;
  unsigned short* a_bf  = (unsigned short*)(ws + off); off += (size_t)BT * D_MODEL * 2;

  k_convert<<<(BT * D_MODEL) / (256 * 8), 256, 0, stream>>>(x, x_bf);
  k_transpose_convert<<<(1024 / 64) * (3072 / 64), 256, 0, stream>>>(wqkv, wq_T, 1024, 3072);
  k_transpose_convert<<<(1024 / 64) * (1024 / 64), 256, 0, stream>>>(wproj, wp_T, 1024, 1024);
  k_qkv_gemm<<<(BT / 128) * (N3D / 128), 256, 0, stream>>>(x_bf, wq_T, bqkv, Qb, Kb, Vt);
  // 64 heads x (T/256)=8 q-blocks = 512 blocks, 512 threads (8 waves)
  k_attn<<<512, 512, 0, stream>>>(Qb, Kb, Vt, a_bf);
  k_proj_gemm<<<(BT / 128) * (D_MODEL / 128), 256, 0, stream>>>(a_bf, wp_T, bproj, (float*)d_out);
}

// Round 5
// 280.029 us; speedup vs baseline: 1.0108x; 1.0108x over previous
//
#include <hip/hip_runtime.h>
#include <hip/hip_bf16.h>

#define T_SEQ   2048
#define D_MODEL 1024
#define N_HEADS 16
#define HEAD_DIM 64
#define BT      8192   // B*T
#define N3D     3072

using short8  = __attribute__((ext_vector_type(8))) short;
using short4v = __attribute__((ext_vector_type(4))) short;
using floatx4 = __attribute__((ext_vector_type(4))) float;

#define QSCALE 0.18033688f  // 0.125 * log2(e): folded into Q at QKV epilogue

__device__ __forceinline__ unsigned short rne_bf16(float f) {
  unsigned int u = __float_as_uint(f);
  u = (u + 0x7fffu + ((u >> 16) & 1u)) >> 16;
  return (unsigned short)u;
}

// async global->LDS, 16B per lane; dest = wave-uniform base + lane*16 (m104)
__device__ __forceinline__ void gload_lds16(const unsigned short* g,
                                            unsigned short* l) {
  __builtin_amdgcn_global_load_lds(
      (const __attribute__((address_space(1))) void*)g,
      (__attribute__((address_space(3))) void*)l, 16, 0, 0);
}

// ---------------- elementwise fp32 -> bf16 ----------------
__global__ __launch_bounds__(256) void k_convert(const float* __restrict__ in,
                                                 unsigned short* __restrict__ out) {
  size_t i = ((size_t)blockIdx.x * 256 + threadIdx.x) * 8;
  float4 a = *(const float4*)(in + i);
  float4 b = *(const float4*)(in + i + 4);
  short8 v;
  v[0] = (short)rne_bf16(a.x); v[1] = (short)rne_bf16(a.y);
  v[2] = (short)rne_bf16(a.z); v[3] = (short)rne_bf16(a.w);
  v[4] = (short)rne_bf16(b.x); v[5] = (short)rne_bf16(b.y);
  v[6] = (short)rne_bf16(b.z); v[7] = (short)rne_bf16(b.w);
  *(short8*)(((short*)out) + i) = v;
}

// ------------- tiled transpose + convert -------------
__global__ __launch_bounds__(256) void k_transpose_convert(
    const float* __restrict__ in, unsigned short* __restrict__ out_hi,
    int R, int C) {
  __shared__ float tile[64][65];
  int tiles_c = C >> 6;
  int r0 = (blockIdx.x / tiles_c) << 6;
  int c0 = (blockIdx.x % tiles_c) << 6;
  int tid = threadIdx.x;
#pragma unroll
  for (int i = 0; i < 16; ++i) {
    int idx = tid + i * 256;
    int r = idx >> 6, c = idx & 63;
    tile[r][c] = in[(size_t)(r0 + r) * C + c0 + c];
  }
  __syncthreads();
#pragma unroll
  for (int i = 0; i < 16; ++i) {
    int idx = tid + i * 256;
    int orow = idx >> 6, oc = idx & 63;
    out_hi[(size_t)(c0 + orow) * R + r0 + oc] = rne_bf16(tile[oc][orow]);
  }
}

// ---------------- QKV GEMM (bf16 MFMA, BK=64, per-block orientation) ------
// R12: each block's 128-wide n-range lies entirely in Q, K, or V
// (1024%128==0), so `which` is block-uniform. Q/K blocks compute the
// TRANSPOSED product (mfma A=W-frag, B=x-frag): C/D rows <- n (hd in the
// register direction), cols <- m (t across lanes). Epilogue then stores
// 16 short4v per thread (8B contiguous, 32B/quad-group) instead of 64
// scalar 2B stores (+their address VALU) -- the R4 post-mortem's
// unaccounted ~30us of epilogue issue time. V blocks keep the original
// orientation (V^T store was already vectorized). K-loop/staging/swizzle
// identical to R11.
__global__ __launch_bounds__(256) void k_qkv_gemm(
    const unsigned short* __restrict__ A, const unsigned short* __restrict__ Bt,
    const float* __restrict__ bias,
    unsigned short* __restrict__ Qo, unsigned short* __restrict__ Ko,
    unsigned short* __restrict__ Vt) {
  __shared__ __align__(16) unsigned short As[128 * 64];
  __shared__ __align__(16) unsigned short Bs[128 * 64];
  int tid = threadIdx.x;
  int wg = (blockIdx.x & 7) * 192 + (blockIdx.x >> 3);  // XCD-chunked, bijective
  int m0 = (wg / 24) * 128;
  int n0 = (wg % 24) * 128;
  int which = n0 >> 10;            // block-uniform: 0=Q 1=K 2=V
  int w = tid >> 6, lane = tid & 63, quad = lane >> 4, l16 = lane & 15;
  int wm = (w >> 1) * 64, wn = (w & 1) * 64;
  floatx4 acc[4][4] = {};

  // staging: slot s = tid + i*256 (i<4); row = s>>3, phys group = s&7,
  // logical group = (s&7) ^ (row&7)
  int r0 = tid >> 3;
  int gsh = (((tid & 7) ^ (r0 & 7)) << 3);   // shorts offset of logical group

  // read offsets: logical group = ks*4+quad at row ra -> phys ^ (ra&7)
  int a_off[4][2], b_off[4][2];
#pragma unroll
  for (int t = 0; t < 4; ++t) {
    int ra = wm + t * 16 + l16, rb = wn + t * 16 + l16;
#pragma unroll
    for (int ks = 0; ks < 2; ++ks) {
      a_off[t][ks] = ra * 64 + (((ks * 4 + quad) ^ (ra & 7)) << 3);
      b_off[t][ks] = rb * 64 + (((ks * 4 + quad) ^ (rb & 7)) << 3);
    }
  }

  for (int k0 = 0; k0 < 1024; k0 += 64) {
#pragma unroll
    for (int i = 0; i < 4; ++i) {
      int sub = (tid & ~63) + i * 256;
      gload_lds16(A + (size_t)(m0 + r0 + i * 32) * 1024 + k0 + gsh,
                  &As[sub * 8]);
      gload_lds16(Bt + (size_t)(n0 + r0 + i * 32) * 1024 + k0 + gsh,
                  &Bs[sub * 8]);
    }
    __syncthreads();
#pragma unroll
    for (int ks = 0; ks < 2; ++ks) {
      short8 af[4], bfr[4];
#pragma unroll
      for (int mt = 0; mt < 4; ++mt) af[mt] = *(const short8*)(&As[a_off[mt][ks]]);
#pragma unroll
      for (int nt = 0; nt < 4; ++nt) bfr[nt] = *(const short8*)(&Bs[b_off[nt][ks]]);
      if (which == 2) {
#pragma unroll
        for (int mt = 0; mt < 4; ++mt)
#pragma unroll
          for (int nt = 0; nt < 4; ++nt)
            acc[mt][nt] = __builtin_amdgcn_mfma_f32_16x16x32_bf16(af[mt], bfr[nt],
                                                                  acc[mt][nt], 0, 0, 0);
      } else {
        // transposed: rows <- n (W), cols <- m (x)
#pragma unroll
        for (int mt = 0; mt < 4; ++mt)
#pragma unroll
          for (int nt = 0; nt < 4; ++nt)
            acc[mt][nt] = __builtin_amdgcn_mfma_f32_16x16x32_bf16(bfr[nt], af[mt],
                                                                  acc[mt][nt], 0, 0, 0);
      }
    }
    __syncthreads();
  }

  if (which == 2) {
    // V path: acc rows=m(t), cols=n(hd). V^T store, t-contiguous.
#pragma unroll
    for (int nt = 0; nt < 4; ++nt) {
      int n = n0 + wn + nt * 16 + l16;
      float bv = bias[n];
      int nn = n & 1023;
      int h = nn >> 6, hd = nn & 63;
#pragma unroll
      for (int mt = 0; mt < 4; ++mt) {
        int mbase = m0 + wm + mt * 16 + quad * 4;
        int b = mbase >> 11;
        int t0 = mbase & 2047;
        int head = b * N_HEADS + h;
        short4v vv;
#pragma unroll
        for (int r = 0; r < 4; ++r) vv[r] = (short)rne_bf16(acc[mt][nt][r] + bv);
        *(short4v*)(&Vt[((size_t)head * HEAD_DIM + hd) * T_SEQ + t0]) = vv;
      }
    }
  } else {
    // Q/K path (transposed acc): rows=n(hd), cols=m(t). hd-contiguous store.
    unsigned short* dst = (which == 0) ? Qo : Ko;
    float scl = (which == 0) ? QSCALE : 1.0f;
#pragma unroll
    for (int nt = 0; nt < 4; ++nt) {
      int nbase = n0 + wn + nt * 16 + quad * 4;    // +r in register dir
      int nn = nbase & 1023;
      int h = nn >> 6, hd0 = nn & 63;
      float4 bv4 = *(const float4*)(&bias[nbase]);
#pragma unroll
      for (int mt = 0; mt < 4; ++mt) {
        int m = m0 + wm + mt * 16 + l16;
        int b = m >> 11;
        int t = m & 2047;
        int head = b * N_HEADS + h;
        short4v ov;
        ov[0] = (short)rne_bf16((acc[mt][nt][0] + bv4.x) * scl);
        ov[1] = (short)rne_bf16((acc[mt][nt][1] + bv4.y) * scl);
        ov[2] = (short)rne_bf16((acc[mt][nt][2] + bv4.z) * scl);
        ov[3] = (short)rne_bf16((acc[mt][nt][3] + bv4.w) * scl);
        *(short4v*)(&dst[((size_t)head * T_SEQ + t) * HEAD_DIM + hd0]) = ov;
      }
    }
  }
}

// ---------------- flash attention (S^T form, T15 pipeline, QBLK=256) -------
// R10 (kept verbatim): 8 waves / 512 threads, 256 q-rows/block, grid 512,
// XCD-grouped heads. 93.5 us steady, FETCH 27MB, MfmaUtil 34.6.
__global__ __launch_bounds__(512, 4) void k_attn(
    const unsigned short* __restrict__ Q, const unsigned short* __restrict__ K,
    const unsigned short* __restrict__ Vt, unsigned short* __restrict__ Oo) {
  __shared__ __align__(16) unsigned short Klds[2][64 * 64];
  __shared__ __align__(16) unsigned short Vlds[3][64 * 64];
  int tid = threadIdx.x;
  int head = ((blockIdx.x & 7) << 3) + (blockIdx.x >> 6);  // XCD-grouped
  int qb = ((blockIdx.x >> 3) & 7) << 8;                   // 256 rows/block
  int b = head >> 4, h = head & 15;
  int w = tid >> 6, lane = tid & 63, quad = lane >> 4, l16 = lane & 15;
  const unsigned short* Qh = Q + (size_t)head * T_SEQ * HEAD_DIM;
  const unsigned short* Kh = K + (size_t)head * T_SEQ * HEAD_DIM;
  const unsigned short* Vh = Vt + (size_t)head * HEAD_DIM * T_SEQ;

  // Q B-frag: lane n=q=l16 holds d-elems quad*8+j (+32 per ks-half)
  short8 qf[2][2];
#pragma unroll
  for (int qi = 0; qi < 2; ++qi) {
    int qrow = qb + w * 32 + qi * 16 + l16;
#pragma unroll
    for (int ks = 0; ks < 2; ++ks)
      qf[qi][ks] = *(const short8*)(Qh + (size_t)qrow * 64 + ks * 32 + quad * 8);
  }

  short8 ones;
#pragma unroll
  for (int j = 0; j < 8; ++j) ones[j] = (short)0x3F80;  // bf16 1.0

  floatx4 O[2][4] = {};
  floatx4 Osum[2] = {};
  const floatx4 zf = {};

  // staging: slot = tid (512 slots x 16B = 8KB tile). Logical index
  // xs = lane ^ sg; K source row applies the tile permutation to xs.
  int sg = tid >> 6;                       // wave-uniform, 0..7
  int xs = lane ^ sg;
  int ntp = xs >> 4, mp = xs & 15;
  int ksrc = ((ntp >> 1) << 5) + ((mp >> 2) << 3) + ((ntp & 1) << 2) + (mp & 3);
  int vsrc = xs;                           // V^T row d
  int sub = tid & ~63;                     // wave-uniform slot base

  // loop-invariant swizzled LDS read offsets (short units): pu[ks][t]
  int pu[2][4];
#pragma unroll
  for (int ks = 0; ks < 2; ++ks) {
    int gk = ks * 4 + quad;
#pragma unroll
    for (int t = 0; t < 4; ++t)
      pu[ks][t] = (((gk << 6) + t * 16 + l16) ^ gk) << 3;
  }

  auto stageK = [&](unsigned short* dst, int kb) {
    gload_lds16(Kh + ((size_t)(kb * 64 + ksrc)) * 64 + sg * 8, dst + sub * 8);
  };
  auto stageV = [&](unsigned short* dst, int kb) {
    gload_lds16(Vh + (size_t)vsrc * T_SEQ + kb * 64 + sg * 8, dst + sub * 8);
  };

  short8 pPrev[2][2];   // P fragments of tile t-1 (carried across iterations)

  auto qk = [&](const unsigned short* Kb_, floatx4 (&s)[2][4]) {
#pragma unroll
    for (int ks = 0; ks < 2; ++ks) {
#pragma unroll
      for (int nt = 0; nt < 4; ++nt) {
        short8 kf = *(const short8*)(Kb_ + pu[ks][nt]);
        if (ks == 0) {
          s[0][nt] = __builtin_amdgcn_mfma_f32_16x16x32_bf16(kf, qf[0][0], zf, 0, 0, 0);
          s[1][nt] = __builtin_amdgcn_mfma_f32_16x16x32_bf16(kf, qf[1][0], zf, 0, 0, 0);
        } else {
          s[0][nt] = __builtin_amdgcn_mfma_f32_16x16x32_bf16(kf, qf[0][1], s[0][nt], 0, 0, 0);
          s[1][nt] = __builtin_amdgcn_mfma_f32_16x16x32_bf16(kf, qf[1][1], s[1][nt], 0, 0, 0);
        }
      }
    }
  };

  auto pv = [&](const unsigned short* Vb_) {
#pragma unroll
    for (int ks = 0; ks < 2; ++ks) {
      Osum[0] = __builtin_amdgcn_mfma_f32_16x16x32_bf16(ones, pPrev[0][ks], Osum[0], 0, 0, 0);
      Osum[1] = __builtin_amdgcn_mfma_f32_16x16x32_bf16(ones, pPrev[1][ks], Osum[1], 0, 0, 0);
#pragma unroll
      for (int dt = 0; dt < 4; ++dt) {
        short8 vf = *(const short8*)(Vb_ + pu[ks][dt]);
        O[0][dt] = __builtin_amdgcn_mfma_f32_16x16x32_bf16(vf, pPrev[0][ks], O[0][dt], 0, 0, 0);
        O[1][dt] = __builtin_amdgcn_mfma_f32_16x16x32_bf16(vf, pPrev[1][ks], O[1][dt], 0, 0, 0);
      }
    }
  };

  auto expPack = [&](floatx4 (&s)[2][4]) {
#pragma unroll
    for (int qi = 0; qi < 2; ++qi) {
      unsigned int dw[4][2];
#pragma unroll
      for (int nt = 0; nt < 4; ++nt) {
        float p0 = __builtin_amdgcn_exp2f(s[qi][nt][0]);
        float p1 = __builtin_amdgcn_exp2f(s[qi][nt][1]);
        float p2 = __builtin_amdgcn_exp2f(s[qi][nt][2]);
        float p3 = __builtin_amdgcn_exp2f(s[qi][nt][3]);
        __hip_bfloat162 lo2 = __float22bfloat162_rn(make_float2(p0, p1));
        __hip_bfloat162 hi2 = __float22bfloat162_rn(make_float2(p2, p3));
        dw[nt][0] = *(unsigned int*)&lo2;
        dw[nt][1] = *(unsigned int*)&hi2;
      }
#pragma unroll
      for (int ks = 0; ks < 2; ++ks) {
        union { unsigned int u[4]; short8 s8; } cv;
        cv.u[0] = dw[2 * ks][0];
        cv.u[1] = dw[2 * ks][1];
        cv.u[2] = dw[2 * ks + 1][0];
        cv.u[3] = dw[2 * ks + 1][1];
        pPrev[qi][ks] = cv.s8;
      }
    }
  };

  unsigned short* Kcur = &Klds[1][0];
  unsigned short* Koth = &Klds[0][0];
  unsigned short* Vp = &Vlds[0][0];
  unsigned short* Vc = &Vlds[1][0];
  unsigned short* Vn = &Vlds[2][0];

  // prologue: tile 0 (QK + pack only, no PV yet)
  stageK(Koth, 0); stageV(Vp, 0);
  __syncthreads();
  stageK(Kcur, 1); stageV(Vc, 1);
  {
    floatx4 s[2][4];
    qk(Koth, s);
    expPack(s);
  }
  __syncthreads();

#pragma unroll 1
  for (int t = 1; t < 32; ++t) {
    if (t < 31) { stageK(Koth, t + 1); stageV(Vn, t + 1); }
    floatx4 s[2][4];
    __builtin_amdgcn_s_setprio(1);
    qk(Kcur, s);        // QK(t)   — matrix pipe
    pv(Vp);             // PV(t-1) — matrix pipe, independent of s
    __builtin_amdgcn_s_setprio(0);
    expPack(s);         // exp2/pack(t) — VALU, overlaps PV drain
    __syncthreads();
    unsigned short* tk = Kcur; Kcur = Koth; Koth = tk;
    unsigned short* tv = Vp; Vp = Vc; Vc = Vn; Vn = tv;
  }
  pv(Vp);               // PV(31)

  // O^T layout: lane col q=l16, rows d = dt*16 + quad*4 + r -> b64 stores
#pragma unroll
  for (int qi = 0; qi < 2; ++qi) {
    float inv = 1.0f / Osum[qi][0];
    int t = qb + w * 32 + qi * 16 + l16;
    size_t rowo = ((size_t)(b * T_SEQ + t)) * D_MODEL + h * HEAD_DIM;
#pragma unroll
    for (int dt = 0; dt < 4; ++dt) {
      short4v ov;
#pragma unroll
      for (int r = 0; r < 4; ++r) ov[r] = (short)rne_bf16(O[qi][dt][r] * inv);
      *(short4v*)(&Oo[rowo + dt * 16 + quad * 4]) = ov;
    }
  }
}

// ---------------- proj GEMM (bf16 MFMA, BK=64, XCD-swizzled grid) ---------
__global__ __launch_bounds__(256) void k_proj_gemm(
    const unsigned short* __restrict__ A, const unsigned short* __restrict__ Bt,
    const float* __restrict__ bias, float* __restrict__ out) {
  __shared__ __align__(16) unsigned short As[128 * 64];
  __shared__ __align__(16) unsigned short Bs[128 * 64];
  int tid = threadIdx.x;
  int wg = (blockIdx.x & 7) * 64 + (blockIdx.x >> 3);   // XCD-chunked, bijective
  int m0 = (wg >> 3) * 128;
  int n0 = (wg & 7) * 128;
  int w = tid >> 6, lane = tid & 63, quad = lane >> 4, l16 = lane & 15;
  int wm = (w >> 1) * 64, wn = (w & 1) * 64;
  floatx4 acc[4][4] = {};

  int r0 = tid >> 3;
  int gsh = (((tid & 7) ^ (r0 & 7)) << 3);

  int a_off[4][2], b_off[4][2];
#pragma unroll
  for (int t = 0; t < 4; ++t) {
    int ra = wm + t * 16 + l16, rb = wn + t * 16 + l16;
#pragma unroll
    for (int ks = 0; ks < 2; ++ks) {
      a_off[t][ks] = ra * 64 + (((ks * 4 + quad) ^ (ra & 7)) << 3);
      b_off[t][ks] = rb * 64 + (((ks * 4 + quad) ^ (rb & 7)) << 3);
    }
  }

  for (int k0 = 0; k0 < 1024; k0 += 64) {
#pragma unroll
    for (int i = 0; i < 4; ++i) {
      int sub = (tid & ~63) + i * 256;
      gload_lds16(A + (size_t)(m0 + r0 + i * 32) * 1024 + k0 + gsh,
                  &As[sub * 8]);
      gload_lds16(Bt + (size_t)(n0 + r0 + i * 32) * 1024 + k0 + gsh,
                  &Bs[sub * 8]);
    }
    __syncthreads();
#pragma unroll
    for (int ks = 0; ks < 2; ++ks) {
      short8 af[4], bfr[4];
#pragma unroll
      for (int mt = 0; mt < 4; ++mt) af[mt] = *(const short8*)(&As[a_off[mt][ks]]);
#pragma unroll
      for (int nt = 0; nt < 4; ++nt) bfr[nt] = *(const short8*)(&Bs[b_off[nt][ks]]);
#pragma unroll
      for (int mt = 0; mt < 4; ++mt)
#pragma unroll
        for (int nt = 0; nt < 4; ++nt)
          acc[mt][nt] = __builtin_amdgcn_mfma_f32_16x16x32_bf16(af[mt], bfr[nt],
                                                                acc[mt][nt], 0, 0, 0);
    }
    __syncthreads();
  }

#pragma unroll
  for (int nt = 0; nt < 4; ++nt) {
    int n = n0 + wn + nt * 16 + l16;
    float bv = bias[n];
#pragma unroll
    for (int mt = 0; mt < 4; ++mt)
#pragma unroll
      for (int r = 0; r < 4; ++r) {
        int m = m0 + wm + mt * 16 + quad * 4 + r;
        out[(size_t)m * 1024 + n] = acc[mt][nt][r] + bv;
      }
  }
}

extern "C" void kernel_launch(void* const* d_in, const int* in_sizes, int n_in,
                              void* d_out, int out_size, void* d_ws, size_t ws_size,
                              hipStream_t stream) {
  const float* x     = (const float*)d_in[0];
  const float* wqkv  = (const float*)d_in[1];
  const float* bqkv  = (const float*)d_in[2];
  const float* wproj = (const float*)d_in[3];
  const float* bproj = (const float*)d_in[4];

  char* ws = (char*)d_ws;
  size_t off = 0;
  unsigned short* x_bf  = (unsigned short*)(ws + off); off += (size_t)BT * D_MODEL * 2;
  unsigned short* wq_T  = (unsigned short*)(ws + off); off += (size_t)N3D * D_MODEL * 2;
  unsigned short* wp_T  = (unsigned short*)(ws + off); off += (size_t)D_MODEL * D_MODEL * 2;
  unsigned short* Qb    = (unsigned short*)(ws + off); off += (size_t)BT * D_MODEL * 2;
  unsigned short* Kb    = (unsigned short*)(ws + off); off += (size_t)BT * D_MODEL * 2;
  unsigned short* Vt    = (unsigned short*)(ws + off); off += (size_t)BT * D_MODEL * 2;
  unsigned short* a_bf  = (unsigned short*)(ws + off); off += (size_t)BT * D_MODEL * 2;

  k_convert<<<(BT * D_MODEL) / (256 * 8), 256, 0, stream>>>(x, x_bf);
  k_transpose_convert<<<(1024 / 64) * (3072 / 64), 256, 0, stream>>>(wqkv, wq_T, 1024, 3072);
  k_transpose_convert<<<(1024 / 64) * (1024 / 64), 256, 0, stream>>>(wproj, wp_T, 1024, 1024);
  k_qkv_gemm<<<(BT / 128) * (N3D / 128), 256, 0, stream>>>(x_bf, wq_T, bqkv, Qb, Kb, Vt);
  // 64 heads x (T/256)=8 q-blocks = 512 blocks, 512 threads (8 waves)
  k_attn<<<512, 512, 0, stream>>>(Qb, Kb, Vt, a_bf);
  k_proj_gemm<<<(BT / 128) * (D_MODEL / 128), 256, 0, stream>>>(a_bf, wp_T, bproj, (float*)d_out);
}